// Round 3
// baseline (41.246 us; speedup 1.0000x reference)
//
#include <hip/hip_runtime.h>

constexpr int N = 512;
constexpr int D = 128;
constexpr float MARGIN = 1.0f;
constexpr float EPS_T = 1e-16f;

// Fused single kernel. One block per anchor i, one k per thread (512 threads).
//  P1: stage e[i] + labels; each thread computes d(i, tid) -> drow LDS
//  P2: wave 0 ballot-compacts positive distances into posd (deterministic)
//  P3: each thread (its k a negative) accumulates hinge over ~16 positives
//  P4: block reduce (f64, fixed tree) -> partial triple in d_ws
//  P5: last-arriving block (device atomicAdd ticket) reduces all 512 triples
//      and writes the two scalar outputs. Ticket zeroed per launch by a
//      hipMemsetAsync node, so every call is identical and state-free.
__global__ __launch_bounds__(512) void triplet_fused_k(
    const float* __restrict__ emb, const int* __restrict__ labels,
    double* __restrict__ partial, unsigned int* __restrict__ ticket,
    float* __restrict__ out)
{
    __shared__ float  ei[D];
    __shared__ float  drow[N];
    __shared__ int    lab[N];
    __shared__ float  posd[N];
    __shared__ int    npos_s;
    __shared__ int    last_s;
    __shared__ double red[24];   // [0..7]=sum, [8..15]=npos, [16..23]=ntrip

    const int i    = blockIdx.x;
    const int tid  = threadIdx.x;
    const int lane = tid & 63;
    const int wid  = tid >> 6;

    if (tid < D) ei[tid] = emb[(size_t)i * D + tid];
    const int lk = labels[tid];          // label of this thread's k (= tid)
    lab[tid] = lk;
    __syncthreads();

    const int li = lab[i];

    // ---- P1: distance d(i, tid) ----
    const float4* ea = reinterpret_cast<const float4*>(ei);
    const float4* ek = reinterpret_cast<const float4*>(emb + (size_t)tid * D);
    float sq = 0.f;
    #pragma unroll
    for (int t = 0; t < D / 4; ++t) {
        float4 v = ek[t];
        float4 a = ea[t];
        float d0 = a.x - v.x, d1 = a.y - v.y;
        float d2 = a.z - v.z, d3 = a.w - v.w;
        sq += d0 * d0 + d1 * d1 + d2 * d2 + d3 * d3;
    }
    const float dik = (sq > 0.f) ? sqrtf(sq) : 0.f;   // safe sqrt per reference
    drow[tid] = dik;
    __syncthreads();

    // ---- P2: deterministic positive-distance compaction (wave 0) ----
    if (wid == 0) {
        int base = 0;
        #pragma unroll
        for (int r = 0; r < 8; ++r) {
            const int j = r * 64 + lane;
            const bool pred = (lab[j] == li) && (j != i);
            const unsigned long long m = __ballot(pred);
            if (pred) posd[base + __popcll(m & ((1ull << lane) - 1ull))] = drow[j];
            base += __popcll(m);
        }
        if (lane == 0) npos_s = base;
    }
    __syncthreads();

    // ---- P3: hinge accumulation (this thread's k is a negative?) ----
    const int npos = npos_s;
    double sum = 0.0;
    int np_i = 0, nt_i = 0;
    if (lk != li) {
        #pragma unroll 4
        for (int p = 0; p < npos; ++p) {
            const float t = (posd[p] - dik) + MARGIN;  // reference op order
            if (t > EPS_T) { sum += (double)t; ++np_i; }
        }
        nt_i = npos;
    }

    // ---- P4: block reduction, fixed tree ----
    double s = sum, p = (double)np_i, t = (double)nt_i;
    #pragma unroll
    for (int off = 32; off > 0; off >>= 1) {
        s += __shfl_down(s, off);
        p += __shfl_down(p, off);
        t += __shfl_down(t, off);
    }
    if (lane == 0) { red[wid] = s; red[8 + wid] = p; red[16 + wid] = t; }
    __syncthreads();
    if (tid == 0) {
        double S = 0.0, P = 0.0, T = 0.0;
        #pragma unroll
        for (int w = 0; w < 8; ++w) { S += red[w]; P += red[8 + w]; T += red[16 + w]; }
        partial[i]         = S;
        partial[N + i]     = P;
        partial[2 * N + i] = T;
        __threadfence();                               // release partials
        last_s = (atomicAdd(ticket, 1u) == (unsigned)(gridDim.x - 1)) ? 1 : 0;
    }
    __syncthreads();                                   // also orders red[] reuse

    // ---- P5: last block finalizes ----
    if (last_s) {
        __threadfence();                               // acquire others' partials
        double a = partial[tid];
        double b = partial[N + tid];
        double c = partial[2 * N + tid];
        #pragma unroll
        for (int off = 32; off > 0; off >>= 1) {
            a += __shfl_down(a, off);
            b += __shfl_down(b, off);
            c += __shfl_down(c, off);
        }
        if (lane == 0) { red[wid] = a; red[8 + wid] = b; red[16 + wid] = c; }
        __syncthreads();
        if (tid == 0) {
            double S = 0.0, P = 0.0, T = 0.0;
            #pragma unroll
            for (int w = 0; w < 8; ++w) { S += red[w]; P += red[8 + w]; T += red[16 + w]; }
            out[0] = (float)(S / (P + 1e-16));         // loss
            out[1] = (float)(P / (T + 1e-16));         // fraction_positive
        }
    }
}

extern "C" void kernel_launch(void* const* d_in, const int* in_sizes, int n_in,
                              void* d_out, int out_size, void* d_ws, size_t ws_size,
                              hipStream_t stream) {
    const float* emb   = (const float*)d_in[0];   // [512,128] f32
    const int*   lab   = (const int*)d_in[1];     // [512] i32
    float*       out   = (float*)d_out;           // [2] f32: loss, fraction_positive

    double*       parts  = (double*)d_ws;                         // 3*N*8 = 12288 B
    unsigned int* ticket = (unsigned int*)((char*)d_ws + 3 * N * sizeof(double));

    hipMemsetAsync(ticket, 0, sizeof(unsigned int), stream);      // deterministic per-call
    triplet_fused_k<<<N, 512, 0, stream>>>(emb, lab, parts, ticket, out);
}

// Round 4
// 36.626 us; speedup vs baseline: 1.1261x; 1.1261x over previous
//
#include <hip/hip_runtime.h>

constexpr int N = 512;
constexpr int D = 128;
constexpr float MARGIN = 1.0f;
constexpr float EPS_T = 1e-16f;

// Fully fused, single dispatch, no reset node.
// One block per anchor i, one k per thread (512 threads).
//  P1: stage e[i]; each thread computes d(i, tid) -> drow LDS
//  P2: wave 0 ballot-compacts positive distances into posd (deterministic)
//  P3: each thread (its k a negative) accumulates hinge over ~16 positives
//  P4: block reduce (f64, fixed tree) -> partial triple in d_ws
//  P5: last-arriving block finalizes. Ticket needs NO per-call reset:
//      each call adds exactly N increments, so (old & (N-1)) == N-1 fires
//      exactly once per call from ANY starting value (mod-N window);
//      the finalizer then stores 0 so steady-state calls are identical.
__global__ __launch_bounds__(512) void triplet_fused_k(
    const float* __restrict__ emb, const int* __restrict__ labels,
    double* __restrict__ partial, unsigned int* __restrict__ ticket,
    float* __restrict__ out)
{
    __shared__ float  ei[D];
    __shared__ float  drow[N];
    __shared__ float  posd[N];
    __shared__ int    npos_s;
    __shared__ int    last_s;
    __shared__ double red[24];   // [0..7]=sum, [8..15]=npos, [16..23]=ntrip

    const int i    = blockIdx.x;
    const int tid  = threadIdx.x;
    const int lane = tid & 63;
    const int wid  = tid >> 6;

    if (tid < D) ei[tid] = emb[(size_t)i * D + tid];
    const int lk = labels[tid];          // this thread's k-label
    const int li = labels[i];            // wave-uniform broadcast load
    __syncthreads();

    // ---- P1: distance d(i, tid) ----
    const float4* ea = reinterpret_cast<const float4*>(ei);
    const float4* ek = reinterpret_cast<const float4*>(emb + (size_t)tid * D);
    float sq = 0.f;
    #pragma unroll
    for (int t = 0; t < D / 4; ++t) {
        float4 v = ek[t];
        float4 a = ea[t];
        float d0 = a.x - v.x, d1 = a.y - v.y;
        float d2 = a.z - v.z, d3 = a.w - v.w;
        sq += d0 * d0 + d1 * d1 + d2 * d2 + d3 * d3;
    }
    const float dik = (sq > 0.f) ? sqrtf(sq) : 0.f;   // safe sqrt per reference
    drow[tid] = dik;
    __syncthreads();

    // ---- P2: deterministic positive-distance compaction (wave 0) ----
    if (wid == 0) {
        int base = 0;
        #pragma unroll
        for (int r = 0; r < 8; ++r) {
            const int j = r * 64 + lane;
            const bool pred = (labels[j] == li) && (j != i);
            const unsigned long long m = __ballot(pred);
            if (pred) posd[base + __popcll(m & ((1ull << lane) - 1ull))] = drow[j];
            base += __popcll(m);
        }
        if (lane == 0) npos_s = base;
    }
    __syncthreads();

    // ---- P3: hinge accumulation (is this thread's k a negative?) ----
    const int npos = npos_s;
    double sum = 0.0;
    int np_i = 0, nt_i = 0;
    if (lk != li) {
        #pragma unroll 4
        for (int p = 0; p < npos; ++p) {
            const float t = (posd[p] - dik) + MARGIN;  // reference op order
            if (t > EPS_T) { sum += (double)t; ++np_i; }
        }
        nt_i = npos;
    }

    // ---- P4: block reduction, fixed tree ----
    double s = sum, p = (double)np_i, t = (double)nt_i;
    #pragma unroll
    for (int off = 32; off > 0; off >>= 1) {
        s += __shfl_down(s, off);
        p += __shfl_down(p, off);
        t += __shfl_down(t, off);
    }
    if (lane == 0) { red[wid] = s; red[8 + wid] = p; red[16 + wid] = t; }
    __syncthreads();
    if (tid == 0) {
        double S = 0.0, P = 0.0, T = 0.0;
        #pragma unroll
        for (int w = 0; w < 8; ++w) { S += red[w]; P += red[8 + w]; T += red[16 + w]; }
        partial[i]         = S;
        partial[N + i]     = P;
        partial[2 * N + i] = T;
        __threadfence();                               // release partials
        const unsigned v = atomicAdd(ticket, 1u);
        last_s = ((v & (unsigned)(N - 1)) == (unsigned)(N - 1)) ? 1 : 0;
    }
    __syncthreads();                                   // also orders red[] reuse

    // ---- P5: last block finalizes ----
    if (last_s) {
        __threadfence();                               // acquire others' partials
        double a = partial[tid];
        double b = partial[N + tid];
        double c = partial[2 * N + tid];
        #pragma unroll
        for (int off = 32; off > 0; off >>= 1) {
            a += __shfl_down(a, off);
            b += __shfl_down(b, off);
            c += __shfl_down(c, off);
        }
        if (lane == 0) { red[wid] = a; red[8 + wid] = b; red[16 + wid] = c; }
        __syncthreads();
        if (tid == 0) {
            double S = 0.0, P = 0.0, T = 0.0;
            #pragma unroll
            for (int w = 0; w < 8; ++w) { S += red[w]; P += red[8 + w]; T += red[16 + w]; }
            out[0] = (float)(S / (P + 1e-16));         // loss
            out[1] = (float)(P / (T + 1e-16));         // fraction_positive
            *ticket = 0;                               // canonical start for next call
        }
    }
}

extern "C" void kernel_launch(void* const* d_in, const int* in_sizes, int n_in,
                              void* d_out, int out_size, void* d_ws, size_t ws_size,
                              hipStream_t stream) {
    const float* emb   = (const float*)d_in[0];   // [512,128] f32
    const int*   lab   = (const int*)d_in[1];     // [512] i32
    float*       out   = (float*)d_out;           // [2] f32: loss, fraction_positive

    double*       parts  = (double*)d_ws;                         // 3*N*8 = 12288 B
    unsigned int* ticket = (unsigned int*)((char*)d_ws + 3 * N * sizeof(double));

    triplet_fused_k<<<N, 512, 0, stream>>>(emb, lab, parts, ticket, out);
}

// Round 5
// 16.033 us; speedup vs baseline: 2.5727x; 2.2845x over previous
//
#include <hip/hip_runtime.h>

constexpr int N = 512;
constexpr int D = 128;
constexpr float MARGIN = 1.0f;
constexpr float EPS_T = 1e-16f;

// Two deterministic kernels (no cross-XCD handoff, no atomics).
// Main: one block per anchor i, 512 threads.
//  P1: COALESCED distance row — 8 lanes per embedding row; lane sub reads
//      float4 chunks {sub, sub+8, sub+16, sub+24}; per 8-lane group that is a
//      contiguous 128-B segment (vs. previous 512-B-strided per-lane rows that
//      touched 64 cache lines per instruction). 8 passes cover all 512 rows.
//  P2: wave 0 ballot-compacts positive distances (deterministic order)
//  P3: thread's k (= tid) if negative: hinge over ~16 positives
//  P4: fixed-tree f64 reduction -> per-block partial triple
// Final: single block reduces the 512 triples, writes the two scalars.
__global__ __launch_bounds__(512) void triplet_main_k(
    const float* __restrict__ emb, const int* __restrict__ labels,
    double* __restrict__ partial)
{
    __shared__ float  ei[D];
    __shared__ float  drow[N];
    __shared__ float  posd[N];
    __shared__ int    npos_s;
    __shared__ double red[24];   // [0..7]=sum, [8..15]=npos, [16..23]=ntrip

    const int i    = blockIdx.x;
    const int tid  = threadIdx.x;
    const int lane = tid & 63;
    const int wid  = tid >> 6;

    if (tid < D) ei[tid] = emb[(size_t)i * D + tid];
    const int lk = labels[tid];          // label of this thread's k (= tid)
    const int li = labels[i];            // uniform broadcast load
    __syncthreads();

    // ---- P1: coalesced distance rows ----
    const float4* ea  = reinterpret_cast<const float4*>(ei);
    const int     sub = tid & 7;         // lane-in-row (8 lanes per row)
    #pragma unroll
    for (int p = 0; p < 8; ++p) {
        const int r = p * 64 + (tid >> 3);
        const float4* er = reinterpret_cast<const float4*>(emb + (size_t)r * D);
        float sq = 0.f;
        #pragma unroll
        for (int c = 0; c < 4; ++c) {
            const int idx = sub + 8 * c;
            float4 v = er[idx];
            float4 a = ea[idx];
            float d0 = a.x - v.x, d1 = a.y - v.y;
            float d2 = a.z - v.z, d3 = a.w - v.w;
            sq += d0 * d0 + d1 * d1 + d2 * d2 + d3 * d3;
        }
        sq += __shfl_xor(sq, 1);
        sq += __shfl_xor(sq, 2);
        sq += __shfl_xor(sq, 4);
        if (sub == 0) drow[r] = (sq > 0.f) ? sqrtf(sq) : 0.f;  // safe sqrt
    }
    __syncthreads();

    // ---- P2: deterministic positive-distance compaction (wave 0) ----
    if (wid == 0) {
        int base = 0;
        #pragma unroll
        for (int r = 0; r < 8; ++r) {
            const int j = r * 64 + lane;
            const bool pred = (labels[j] == li) && (j != i);
            const unsigned long long m = __ballot(pred);
            if (pred) posd[base + __popcll(m & ((1ull << lane) - 1ull))] = drow[j];
            base += __popcll(m);
        }
        if (lane == 0) npos_s = base;
    }
    __syncthreads();

    // ---- P3: hinge accumulation (this thread's k a negative?) ----
    const int   npos = npos_s;
    const float dik  = drow[tid];
    double sum = 0.0;
    int np_i = 0, nt_i = 0;
    if (lk != li) {
        #pragma unroll 4
        for (int p = 0; p < npos; ++p) {
            const float t = (posd[p] - dik) + MARGIN;  // reference op order
            if (t > EPS_T) { sum += (double)t; ++np_i; }
        }
        nt_i = npos;
    }

    // ---- P4: fixed-tree reduction ----
    double s = sum, p = (double)np_i, t = (double)nt_i;
    #pragma unroll
    for (int off = 32; off > 0; off >>= 1) {
        s += __shfl_down(s, off);
        p += __shfl_down(p, off);
        t += __shfl_down(t, off);
    }
    if (lane == 0) { red[wid] = s; red[8 + wid] = p; red[16 + wid] = t; }
    __syncthreads();
    if (tid == 0) {
        double S = 0.0, P = 0.0, T = 0.0;
        #pragma unroll
        for (int w = 0; w < 8; ++w) { S += red[w]; P += red[8 + w]; T += red[16 + w]; }
        partial[i]         = S;
        partial[N + i]     = P;
        partial[2 * N + i] = T;
    }
}

__global__ __launch_bounds__(512) void triplet_final_k(
    const double* __restrict__ partial, float* __restrict__ out)
{
    __shared__ double red[24];
    const int tid  = threadIdx.x;
    const int lane = tid & 63;
    const int wid  = tid >> 6;
    double a = partial[tid];
    double b = partial[N + tid];
    double c = partial[2 * N + tid];
    #pragma unroll
    for (int off = 32; off > 0; off >>= 1) {
        a += __shfl_down(a, off);
        b += __shfl_down(b, off);
        c += __shfl_down(c, off);
    }
    if (lane == 0) { red[wid] = a; red[8 + wid] = b; red[16 + wid] = c; }
    __syncthreads();
    if (tid == 0) {
        double S = 0.0, P = 0.0, T = 0.0;
        #pragma unroll
        for (int w = 0; w < 8; ++w) { S += red[w]; P += red[8 + w]; T += red[16 + w]; }
        out[0] = (float)(S / (P + 1e-16));  // loss
        out[1] = (float)(P / (T + 1e-16));  // fraction_positive
    }
}

extern "C" void kernel_launch(void* const* d_in, const int* in_sizes, int n_in,
                              void* d_out, int out_size, void* d_ws, size_t ws_size,
                              hipStream_t stream) {
    const float* emb   = (const float*)d_in[0];   // [512,128] f32
    const int*   lab   = (const int*)d_in[1];     // [512] i32
    float*       out   = (float*)d_out;           // [2] f32: loss, fraction_positive
    double*      parts = (double*)d_ws;           // 3*N doubles = 12 KB

    triplet_main_k<<<N, 512, 0, stream>>>(emb, lab, parts);
    triplet_final_k<<<1, 512, 0, stream>>>(parts, out);
}